// Round 10
// baseline (174.956 us; speedup 1.0000x reference)
//
#include <hip/hip_runtime.h>

// Problem constants
#define BB 4
#define SS 2048
#define EE 640
#define NHH 10
#define DHH 64
#define MTOK 8192   // BB*SS
#define E33 1920

// exp2 intrinsic (native v_exp_f32)
#if __has_builtin(__builtin_amdgcn_exp2f)
#define EXP2(x) __builtin_amdgcn_exp2f(x)
#else
#define EXP2(x) exp2f(x)
#endif

#define QSCALE 0.18033688011112042f   // 0.125 * log2(e): folds softmax scale + exp->exp2 into Q

typedef float f32x4 __attribute__((ext_vector_type(4)));
typedef __bf16 bf16x8 __attribute__((ext_vector_type(8)));
typedef __bf16 bf16x4 __attribute__((ext_vector_type(4)));
typedef unsigned short u16;
typedef u16 u16x4 __attribute__((ext_vector_type(4)));

__device__ inline u16 f2bf(float f) {
  unsigned u = __builtin_bit_cast(unsigned, f);
  u += 0x7fffu + ((u >> 16) & 1u);   // round-to-nearest-even
  return (u16)(u >> 16);
}

// async global->LDS, 16B per lane; LDS dest = wave-uniform base + lane*16
__device__ __forceinline__ void gl_lds16(const u16* g, u16* l) {
  __builtin_amdgcn_global_load_lds(
      (const __attribute__((address_space(1))) unsigned int*)g,
      (__attribute__((address_space(3))) unsigned int*)l, 16, 0, 0);
}

// ---------------------------------------------------------------- convert
// All three fp32->bf16 conversions in ONE launch.
#define XN4   1310720   // 4*2048*640 / 4
#define WQN4   307200   // 1920*640 / 4
#define WPN4   102400   // 640*640 / 4
__global__ void convert_all(const float* __restrict__ x, const float* __restrict__ wqkv,
                            const float* __restrict__ wproj,
                            u16* __restrict__ xb, u16* __restrict__ wqkvb,
                            u16* __restrict__ wprojb) {
  int i = blockIdx.x * blockDim.x + threadIdx.x;
  const float* src; u16* dst; int off;
  if (i < XN4)              { src = x;     dst = xb;     off = i; }
  else if (i < XN4 + WQN4)  { src = wqkv;  dst = wqkvb;  off = i - XN4; }
  else if (i < XN4 + WQN4 + WPN4) { src = wproj; dst = wprojb; off = i - XN4 - WQN4; }
  else return;
  float4 v = ((const float4*)src)[off];
  u16x4 o = { f2bf(v.x), f2bf(v.y), f2bf(v.z), f2bf(v.w) };
  ((u16x4*)dst)[off] = o;
}

// ---------------------------------------------------------------- QKV GEMM
// R9-exact (settled).  Double-buffered LDS + global_load_lds one tile ahead,
// one barrier per K-step; XOR swizzle (group ^= row&7) on source + read.
// Q pre-scaled by 0.125*log2e so attention softmax runs in exp2 domain.
__global__ __launch_bounds__(256) void gemm_qkv(
    const u16* __restrict__ A, const u16* __restrict__ Bt,
    u16* __restrict__ qb, u16* __restrict__ kb, u16* __restrict__ vt) {
  __shared__ __align__(16) u16 As[2][128 * 64];
  __shared__ __align__(16) u16 Bs[2][128 * 64];
  const int t = threadIdx.x;
  const int m0 = blockIdx.y * 128;
  const int n0 = blockIdx.x * 128;
  const int w = t >> 6, lane = t & 63, n16 = lane & 15, quad = lane >> 4;
  const int wm = w >> 1, wn = w & 1;

  const int sub = lane >> 3, cL = lane & 7;
  const int srcColE = (cL ^ sub) * 8;
  const int rd0 = (quad ^ (n16 & 7)) * 8;
  const int rd1 = ((4 + quad) ^ (n16 & 7)) * 8;

  f32x4 acc[4][4];
  for (int i = 0; i < 4; i++)
    for (int j = 0; j < 4; j++) acc[i][j] = f32x4{0.f, 0.f, 0.f, 0.f};

  // prologue: stage K-tile 0 into buffer 0 (only fully-exposed latency)
#pragma unroll
  for (int i = 0; i < 4; ++i) {
    int c = w * 4 + i, row = c * 8 + sub;
    gl_lds16(&A[(m0 + row) * 640 + srcColE], &As[0][c * 512]);
    gl_lds16(&Bt[(n0 + row) * 640 + srcColE], &Bs[0][c * 512]);
  }
  __syncthreads();                        // vmcnt(0) drain -> buf0 ready

  for (int kt = 0; kt < 10; ++kt) {       // K=640, BK=64
    const int cur = kt & 1, nxt = cur ^ 1;
    if (kt < 9) {                         // issue next-tile DMA (in flight)
#pragma unroll
      for (int i = 0; i < 4; ++i) {
        int c = w * 4 + i, row = c * 8 + sub;
        gl_lds16(&A[(m0 + row) * 640 + (kt + 1) * 64 + srcColE], &As[nxt][c * 512]);
        gl_lds16(&Bt[(n0 + row) * 640 + (kt + 1) * 64 + srcColE], &Bs[nxt][c * 512]);
      }
    }
#pragma unroll
    for (int ks = 0; ks < 2; ++ks) {
      const int rd = ks ? rd1 : rd0;
      bf16x8 a[4], b[4];
      for (int mi = 0; mi < 4; mi++)
        a[mi] = *(const bf16x8*)&As[cur][(wm * 64 + mi * 16 + n16) * 64 + rd];
      for (int ni = 0; ni < 4; ni++)
        b[ni] = *(const bf16x8*)&Bs[cur][(wn * 64 + ni * 16 + n16) * 64 + rd];
      for (int mi = 0; mi < 4; mi++)
        for (int ni = 0; ni < 4; ni++)
          acc[mi][ni] = __builtin_amdgcn_mfma_f32_16x16x32_bf16(a[mi], b[ni], acc[mi][ni], 0, 0, 0);
    }
    __syncthreads();                      // drains this step's DMA; publishes nxt
  }

  const int which = n0 / 640;
  for (int ni = 0; ni < 4; ni++) {
    int col = n0 + wn * 64 + ni * 16 + n16;
    int eh = col - which * 640;
    int h = eh >> 6, d = eh & 63;
    for (int mi = 0; mi < 4; mi++) {
      int tb = m0 + wm * 64 + mi * 16 + quad * 4;   // 4 consecutive tokens (r=0..3)
      f32x4 c = acc[mi][ni];
      if (which == 0) {   // uniform branch: pre-scale Q for exp2-domain softmax
        c[0] *= QSCALE; c[1] *= QSCALE; c[2] *= QSCALE; c[3] *= QSCALE;
      }
      if (which == 2) {
        int b_ = tb >> 11, s_ = tb & 2047;
        u16x4 pk = { f2bf(c[0]), f2bf(c[1]), f2bf(c[2]), f2bf(c[3]) };
        *(u16x4*)&vt[((b_ * NHH + h) * DHH + d) * SS + s_] = pk;
      } else {
        u16* dst = (which == 0) ? qb : kb;
        for (int r = 0; r < 4; r++) {
          int tok = tb + r;
          int b_ = tok >> 11, s_ = tok & 2047;
          dst[((b_ * NHH + h) * SS + s_) * DHH + d] = f2bf(c[r]);
        }
      }
    }
  }
}

// ---------------------------------------------------------------- attention
// R6/R9 structure, but LDS stride 72 -> 64 with XOR bank-swizzle
// (group ^= row&7, same involution as the GEMM staging): K/V double-buffer
// shrinks 36.9KB -> 32.0KB, exactly 5 blocks/CU (was 4) -> +25% resident
// waves for latency hiding on the serial softmax chain.
// One block: 64 q rows of one (b,h); 4 waves x 16 q rows.  S^T = K*Q^T trick;
// softmax in log2 domain; T13 defer-max; one-tile-ahead register prefetch.
__global__ __launch_bounds__(256) void attn_kernel(
    const u16* __restrict__ qb, const u16* __restrict__ kb, const u16* __restrict__ vt,
    u16* __restrict__ y) {
  __shared__ __align__(16) u16 Ks[2][64 * 64];   // K[perm(key)][swz(d)], dbuf
  __shared__ __align__(16) u16 Vs[2][64 * 64];   // V^T[d][swz(key)], dbuf
  const int t = threadIdx.x;
  const int w = t >> 6, lane = t & 63, n16 = lane & 15, quad = lane >> 4;
  const int bh = blockIdx.x;
  const int qt = 31 - blockIdx.y;        // longest blocks first
  const int qb0 = qt * 64;
  const int b_ = bh / NHH, h = bh % NHH;

  // Q fragment (B-operand of S^T): B[n=q][k=d], q = qb0 + w*16 + n16
  bf16x8 aq[2];
  {
    const u16* qp = &qb[(bh * SS + qb0 + w * 16 + n16) * DHH];
    aq[0] = *(const bf16x8*)&qp[quad * 8];
    aq[1] = *(const bf16x8*)&qp[32 + quad * 8];
  }
  const int q_rel = w * 16 + n16;

  // staging: each thread moves 2x16B of K and 2x16B of V per tile
  const int c1 = 256 + t;
  const int row0 = t >> 3,  g0 = t & 7;        // row, 16B col-group
  const int row1 = c1 >> 3, g1 = c1 & 7;
  // key -> permuted LDS row: key = p*32 + quad*8 + b*4 + r  ->  (2p+b)*16 + quad*4 + r
  auto perm = [](int k) {
    int p = k >> 5, rem = k & 31, qd = rem >> 3, tt = rem & 7;
    return ((p << 1) | (tt >> 2)) * 16 + qd * 4 + (tt & 3);
  };
  const int prow0 = perm(row0), prow1 = perm(row1);
  // swizzled element offsets: col-group g at row r lives at (g ^ (r&7))*8
  const int kw0 = prow0 * 64 + ((g0 ^ (prow0 & 7)) * 8);
  const int kw1 = prow1 * 64 + ((g1 ^ (prow1 & 7)) * 8);
  const int vw0 = row0 * 64 + ((g0 ^ (row0 & 7)) * 8);
  const int vw1 = row1 * 64 + ((g1 ^ (row1 & 7)) * 8);
  const int col0 = g0 * 8, col1 = g1 * 8;      // global source cols (unswizzled)
  // swizzled read col offsets: group (4*ks+quad) at row parity n16&7
  const int rdA = (quad ^ (n16 & 7)) * 8;        // ks/p2 = 0
  const int rdB = ((4 + quad) ^ (n16 & 7)) * 8;  // ks/p2 = 1

  float4 fk0, fk1, fv0, fv1;
  fk0 = *(const float4*)&kb[(bh * SS + row0) * DHH + col0];
  fk1 = *(const float4*)&kb[(bh * SS + row1) * DHH + col1];
  fv0 = *(const float4*)&vt[(bh * DHH + row0) * SS + col0];
  fv1 = *(const float4*)&vt[(bh * DHH + row1) * SS + col1];
  *(float4*)&Ks[0][kw0] = fk0;
  *(float4*)&Ks[0][kw1] = fk1;
  *(float4*)&Vs[0][vw0] = fv0;
  *(float4*)&Vs[0][vw1] = fv1;

  float m_i = -1e30f, l_i = 0.f;
  f32x4 o[4];
  for (int db = 0; db < 4; db++) o[db] = f32x4{0.f, 0.f, 0.f, 0.f};

  for (int kt = 0; kt <= qt; ++kt) {
    __syncthreads();
    const int cur = kt & 1, nxt = cur ^ 1;
    if (kt < qt) {   // prefetch next tile (latency hidden behind compute)
      int kk = (kt + 1) * 64;
      fk0 = *(const float4*)&kb[(bh * SS + kk + row0) * DHH + col0];
      fk1 = *(const float4*)&kb[(bh * SS + kk + row1) * DHH + col1];
      fv0 = *(const float4*)&vt[(bh * DHH + row0) * SS + kk + col0];
      fv1 = *(const float4*)&vt[(bh * DHH + row1) * SS + kk + col1];
    }

    // S^T = K * Q^T : A=K (m=permuted key), B=Q (n=q); log2-domain scores
    f32x4 sc[4];
#pragma unroll
    for (int nb = 0; nb < 4; nb++) {
      f32x4 c = f32x4{0.f, 0.f, 0.f, 0.f};
      bf16x8 ak0 = *(const bf16x8*)&Ks[cur][(nb * 16 + n16) * 64 + rdA];
      c = __builtin_amdgcn_mfma_f32_16x16x32_bf16(ak0, aq[0], c, 0, 0, 0);
      bf16x8 ak1 = *(const bf16x8*)&Ks[cur][(nb * 16 + n16) * 64 + rdB];
      c = __builtin_amdgcn_mfma_f32_16x16x32_bf16(ak1, aq[1], c, 0, 0, 0);
      sc[nb] = c;
    }

    // causal mask only on the diagonal tile (uniform branch)
    if (kt == qt) {
#pragma unroll
      for (int nb = 0; nb < 4; nb++)
#pragma unroll
        for (int r = 0; r < 4; r++) {
          int key = ((nb >> 1) << 5) + quad * 8 + ((nb & 1) << 2) + r;
          if (key > q_rel) sc[nb][r] = -1e30f;
        }
    }

    // tile max (tree, v_max3-friendly), replicated over the 4 quads
    f32x4 mx;
#pragma unroll
    for (int r = 0; r < 4; r++)
      mx[r] = fmaxf(fmaxf(sc[0][r], sc[1][r]), fmaxf(sc[2][r], sc[3][r]));
    float rm = fmaxf(fmaxf(mx[0], mx[1]), fmaxf(mx[2], mx[3]));
    rm = fmaxf(rm, __shfl_xor(rm, 16));
    rm = fmaxf(rm, __shfl_xor(rm, 32));

    // T13 defer-max: skip the O/l rescale unless some lane's max grew by >8
    if (!__all(rm - m_i <= 8.0f)) {
      float mnew = fmaxf(m_i, rm);
      float alpha = EXP2(m_i - mnew);
      l_i *= alpha;
#pragma unroll
      for (int db = 0; db < 4; db++)
#pragma unroll
        for (int r = 0; r < 4; r++) o[db][r] *= alpha;
      m_i = mnew;
    }

    // P = 2^(S - m): 16 sub + 16 v_exp, row-sum via tree
    f32x4 ps[4];
#pragma unroll
    for (int nb = 0; nb < 4; nb++)
#pragma unroll
      for (int r = 0; r < 4; r++) ps[nb][r] = EXP2(sc[nb][r] - m_i);
    f32x4 sv;
#pragma unroll
    for (int r = 0; r < 4; r++)
      sv[r] = (ps[0][r] + ps[1][r]) + (ps[2][r] + ps[3][r]);
    float rs = (sv[0] + sv[1]) + (sv[2] + sv[3]);
    rs += __shfl_xor(rs, 16);
    rs += __shfl_xor(rs, 32);
    l_i += rs;

    // O^T += V^T * P^T : A=V^T (m=d), B=P^T (n=q, k=key) -- P already in B layout
#pragma unroll
    for (int p2 = 0; p2 < 2; p2++) {
      bf16x8 bp;
#pragma unroll
      for (int j = 0; j < 4; j++) {
        bp[j]     = (__bf16)ps[2 * p2][j];
        bp[4 + j] = (__bf16)ps[2 * p2 + 1][j];
      }
      const int rdV = p2 ? rdB : rdA;
#pragma unroll
      for (int db = 0; db < 4; db++) {
        bf16x8 av = *(const bf16x8*)&Vs[cur][(db * 16 + n16) * 64 + rdV];
        o[db] = __builtin_amdgcn_mfma_f32_16x16x32_bf16(av, bp, o[db], 0, 0, 0);
      }
    }

    if (kt < qt) {   // write prefetched tile into the other buffer
      *(float4*)&Ks[nxt][kw0] = fk0;
      *(float4*)&Ks[nxt][kw1] = fk1;
      *(float4*)&Vs[nxt][vw0] = fv0;
      *(float4*)&Vs[nxt][vw1] = fv1;
    }
  }

  // epilogue: O^T[d][q] -> y[token][h*64+d]; lane owns q = q_rel, d = db*16+quad*4+r
  const float inv = 1.0f / l_i;
  const int tok = b_ * SS + qb0 + w * 16 + n16;
#pragma unroll
  for (int db = 0; db < 4; db++) {
    bf16x4 pk = { (__bf16)(o[db][0] * inv), (__bf16)(o[db][1] * inv),
                  (__bf16)(o[db][2] * inv), (__bf16)(o[db][3] * inv) };
    *(bf16x4*)&y[tok * EE + h * DHH + db * 16 + quad * 4] = pk;
  }
}

// ---------------------------------------------------------------- proj GEMM
// R9-exact.  out[8192,640] fp32 = y[8192,640] * wproj[640,640]^T
__global__ __launch_bounds__(256) void gemm_proj(
    const u16* __restrict__ A, const u16* __restrict__ Bt, float* __restrict__ out) {
  __shared__ __align__(16) u16 As[2][128 * 64];
  __shared__ __align__(16) u16 Bs[2][128 * 64];
  const int t = threadIdx.x;
  const int m0 = blockIdx.y * 128;
  const int n0 = blockIdx.x * 128;
  const int w = t >> 6, lane = t & 63, n16 = lane & 15, quad = lane >> 4;
  const int wm = w >> 1, wn = w & 1;

  const int sub = lane >> 3, cL = lane & 7;
  const int srcColE = (cL ^ sub) * 8;
  const int rd0 = (quad ^ (n16 & 7)) * 8;
  const int rd1 = ((4 + quad) ^ (n16 & 7)) * 8;

  f32x4 acc[4][4];
  for (int i = 0; i < 4; i++)
    for (int j = 0; j < 4; j++) acc[i][j] = f32x4{0.f, 0.f, 0.f, 0.f};

#pragma unroll
  for (int i = 0; i < 4; ++i) {
    int c = w * 4 + i, row = c * 8 + sub;
    gl_lds16(&A[(m0 + row) * 640 + srcColE], &As[0][c * 512]);
    gl_lds16(&Bt[(n0 + row) * 640 + srcColE], &Bs[0][c * 512]);
  }
  __syncthreads();

  for (int kt = 0; kt < 10; ++kt) {
    const int cur = kt & 1, nxt = cur ^ 1;
    if (kt < 9) {
#pragma unroll
      for (int i = 0; i < 4; ++i) {
        int c = w * 4 + i, row = c * 8 + sub;
        gl_lds16(&A[(m0 + row) * 640 + (kt + 1) * 64 + srcColE], &As[nxt][c * 512]);
        gl_lds16(&Bt[(n0 + row) * 640 + (kt + 1) * 64 + srcColE], &Bs[nxt][c * 512]);
      }
    }
#pragma unroll
    for (int ks = 0; ks < 2; ++ks) {
      const int rd = ks ? rd1 : rd0;
      bf16x8 a[4], b[4];
      for (int mi = 0; mi < 4; mi++)
        a[mi] = *(const bf16x8*)&As[cur][(wm * 64 + mi * 16 + n16) * 64 + rd];
      for (int ni = 0; ni < 4; ni++)
        b[ni] = *(const bf16x8*)&Bs[cur][(wn * 64 + ni * 16 + n16) * 64 + rd];
      for (int mi = 0; mi < 4; mi++)
        for (int ni = 0; ni < 4; ni++)
          acc[mi][ni] = __builtin_amdgcn_mfma_f32_16x16x32_bf16(a[mi], b[ni], acc[mi][ni], 0, 0, 0);
    }
    __syncthreads();
  }

  for (int ni = 0; ni < 4; ni++) {
    int col = n0 + wn * 64 + ni * 16 + n16;
    for (int mi = 0; mi < 4; mi++) {
      int rowb = m0 + wm * 64 + mi * 16 + quad * 4;
      f32x4 c = acc[mi][ni];
      for (int r = 0; r < 4; r++) out[(rowb + r) * 640 + col] = c[r];
    }
  }
}

// ---------------------------------------------------------------- launch
extern "C" void kernel_launch(void* const* d_in, const int* in_sizes, int n_in,
                              void* d_out, int out_size, void* d_ws, size_t ws_size,
                              hipStream_t stream) {
  const float* x     = (const float*)d_in[0];   // [4,2048,640]
  const float* wqkv  = (const float*)d_in[1];   // [1920,640]
  const float* wproj = (const float*)d_in[2];   // [640,640]
  float* out = (float*)d_out;

  char* ws = (char*)d_ws;
  u16* xb     = (u16*)(ws + 0);            // 10,485,760 B
  u16* wqkvb  = (u16*)(ws + 10485760);     //  2,457,600 B
  u16* wprojb = (u16*)(ws + 12943360);     //    819,200 B
  u16* qbuf   = (u16*)(ws + 13762560);     // 10,485,760 B  [bh][s][d]
  u16* kbuf   = (u16*)(ws + 24248320);     // 10,485,760 B  [bh][s][d]
  u16* vtb    = (u16*)(ws + 34734080);     // 10,485,760 B  [bh][d][s]
  u16* ybuf   = (u16*)(ws + 45219840);     // 10,485,760 B  [tok][e]

  convert_all<<<6720, 256, 0, stream>>>(x, wqkv, wproj, xb, wqkvb, wprojb);

  gemm_qkv<<<dim3(15, 64), 256, 0, stream>>>(xb, wqkvb, qbuf, kbuf, vtb);
  attn_kernel<<<dim3(40, 32), 256, 0, stream>>>(qbuf, kbuf, vtb, ybuf);
  gemm_proj<<<dim3(5, 64), 256, 0, stream>>>(ybuf, wprojb, out);
}

// Round 11
// 166.556 us; speedup vs baseline: 1.0504x; 1.0504x over previous
//
#include <hip/hip_runtime.h>

// Problem constants
#define BB 4
#define SS 2048
#define EE 640
#define NHH 10
#define DHH 64
#define MTOK 8192   // BB*SS
#define E33 1920

// exp2 intrinsic (native v_exp_f32)
#if __has_builtin(__builtin_amdgcn_exp2f)
#define EXP2(x) __builtin_amdgcn_exp2f(x)
#else
#define EXP2(x) exp2f(x)
#endif

#define QSCALE 0.18033688011112042f   // 0.125 * log2(e): folds softmax scale + exp->exp2 into Q

typedef float f32x4 __attribute__((ext_vector_type(4)));
typedef __bf16 bf16x8 __attribute__((ext_vector_type(8)));
typedef __bf16 bf16x4 __attribute__((ext_vector_type(4)));
typedef unsigned short u16;
typedef u16 u16x4 __attribute__((ext_vector_type(4)));

// fp32 -> bf16 bits via native cast (RTNE; compiler fuses pairs to v_cvt_pk_bf16_f32)
__device__ inline u16 bfbits(float f) {
  return __builtin_bit_cast(u16, (__bf16)f);
}

// async global->LDS, 16B per lane; LDS dest = wave-uniform base + lane*16
__device__ __forceinline__ void gl_lds16(const u16* g, u16* l) {
  __builtin_amdgcn_global_load_lds(
      (const __attribute__((address_space(1))) unsigned int*)g,
      (__attribute__((address_space(3))) unsigned int*)l, 16, 0, 0);
}

// ---------------------------------------------------------------- convert
// All three fp32->bf16 conversions in ONE launch.
#define XN4   1310720   // 4*2048*640 / 4
#define WQN4   307200   // 1920*640 / 4
#define WPN4   102400   // 640*640 / 4
__global__ void convert_all(const float* __restrict__ x, const float* __restrict__ wqkv,
                            const float* __restrict__ wproj,
                            u16* __restrict__ xb, u16* __restrict__ wqkvb,
                            u16* __restrict__ wprojb) {
  int i = blockIdx.x * blockDim.x + threadIdx.x;
  const float* src; u16* dst; int off;
  if (i < XN4)              { src = x;     dst = xb;     off = i; }
  else if (i < XN4 + WQN4)  { src = wqkv;  dst = wqkvb;  off = i - XN4; }
  else if (i < XN4 + WQN4 + WPN4) { src = wproj; dst = wprojb; off = i - XN4 - WQN4; }
  else return;
  float4 v = ((const float4*)src)[off];
  u16x4 o = { bfbits(v.x), bfbits(v.y), bfbits(v.z), bfbits(v.w) };
  ((u16x4*)dst)[off] = o;
}

// ---------------------------------------------------------------- QKV GEMM
// C[8192,1920] = A[8192,640] * Bt[1920,640]^T, scatter into q/k/v^T buffers.
// R9 structure (dbuf LDS + global_load_lds one tile ahead, one barrier/K-step,
// XOR swizzle on source+read) + T1 XCD-chunked block swizzle: grid 960 = 8*120,
// each XCD owns 8 complete A-row-panels (8*164KB + B 2.5MB < 4MB L2), so an
// A-panel is fetched into exactly ONE private L2 instead of ~8.
// Q pre-scaled by 0.125*log2e so attention softmax runs in exp2 domain.
__global__ __launch_bounds__(256) void gemm_qkv(
    const u16* __restrict__ A, const u16* __restrict__ Bt,
    u16* __restrict__ qb, u16* __restrict__ kb, u16* __restrict__ vt) {
  __shared__ __align__(16) u16 As[2][128 * 64];
  __shared__ __align__(16) u16 Bs[2][128 * 64];
  const int t = threadIdx.x;
  // XCD-chunked bijection (nwg=960, 960/8=120 exact)
  const int orig = blockIdx.x;
  const int newid = (orig & 7) * 120 + (orig >> 3);
  const int m0 = (newid / 15) * 128;
  const int n0 = (newid % 15) * 128;
  const int w = t >> 6, lane = t & 63, n16 = lane & 15, quad = lane >> 4;
  const int wm = w >> 1, wn = w & 1;

  const int sub = lane >> 3, cL = lane & 7;
  const int srcColE = (cL ^ sub) * 8;
  const int rd0 = (quad ^ (n16 & 7)) * 8;
  const int rd1 = ((4 + quad) ^ (n16 & 7)) * 8;

  f32x4 acc[4][4];
  for (int i = 0; i < 4; i++)
    for (int j = 0; j < 4; j++) acc[i][j] = f32x4{0.f, 0.f, 0.f, 0.f};

  // prologue: stage K-tile 0 into buffer 0 (only fully-exposed latency)
#pragma unroll
  for (int i = 0; i < 4; ++i) {
    int c = w * 4 + i, row = c * 8 + sub;
    gl_lds16(&A[(m0 + row) * 640 + srcColE], &As[0][c * 512]);
    gl_lds16(&Bt[(n0 + row) * 640 + srcColE], &Bs[0][c * 512]);
  }
  __syncthreads();                        // vmcnt(0) drain -> buf0 ready

  for (int kt = 0; kt < 10; ++kt) {       // K=640, BK=64
    const int cur = kt & 1, nxt = cur ^ 1;
    if (kt < 9) {                         // issue next-tile DMA (in flight)
#pragma unroll
      for (int i = 0; i < 4; ++i) {
        int c = w * 4 + i, row = c * 8 + sub;
        gl_lds16(&A[(m0 + row) * 640 + (kt + 1) * 64 + srcColE], &As[nxt][c * 512]);
        gl_lds16(&Bt[(n0 + row) * 640 + (kt + 1) * 64 + srcColE], &Bs[nxt][c * 512]);
      }
    }
#pragma unroll
    for (int ks = 0; ks < 2; ++ks) {
      const int rd = ks ? rd1 : rd0;
      bf16x8 a[4], b[4];
      for (int mi = 0; mi < 4; mi++)
        a[mi] = *(const bf16x8*)&As[cur][(wm * 64 + mi * 16 + n16) * 64 + rd];
      for (int ni = 0; ni < 4; ni++)
        b[ni] = *(const bf16x8*)&Bs[cur][(wn * 64 + ni * 16 + n16) * 64 + rd];
      for (int mi = 0; mi < 4; mi++)
        for (int ni = 0; ni < 4; ni++)
          acc[mi][ni] = __builtin_amdgcn_mfma_f32_16x16x32_bf16(a[mi], b[ni], acc[mi][ni], 0, 0, 0);
    }
    __syncthreads();                      // drains this step's DMA; publishes nxt
  }

  const int which = n0 / 640;
  for (int ni = 0; ni < 4; ni++) {
    int col = n0 + wn * 64 + ni * 16 + n16;
    int eh = col - which * 640;
    int h = eh >> 6, d = eh & 63;
    for (int mi = 0; mi < 4; mi++) {
      int tb = m0 + wm * 64 + mi * 16 + quad * 4;   // 4 consecutive tokens (r=0..3)
      f32x4 c = acc[mi][ni];
      if (which == 0) {   // uniform branch: pre-scale Q for exp2-domain softmax
        c[0] *= QSCALE; c[1] *= QSCALE; c[2] *= QSCALE; c[3] *= QSCALE;
      }
      if (which == 2) {
        int b_ = tb >> 11, s_ = tb & 2047;
        u16x4 pk = { bfbits(c[0]), bfbits(c[1]), bfbits(c[2]), bfbits(c[3]) };
        *(u16x4*)&vt[((b_ * NHH + h) * DHH + d) * SS + s_] = pk;
      } else {
        u16* dst = (which == 0) ? qb : kb;
        for (int r = 0; r < 4; r++) {
          int tok = tb + r;
          int b_ = tok >> 11, s_ = tok & 2047;
          dst[((b_ * NHH + h) * SS + s_) * DHH + d] = bfbits(c[r]);
        }
      }
    }
  }
}

// ---------------------------------------------------------------- attention
// R10-exact (49.0us, bank-conflicts 0).  One block: 64 q rows of one (b,h);
// 4 waves x 16 q rows.  S^T = K*Q^T trick; softmax in log2 domain; T13
// defer-max; stride-64 XOR-swizzled K/V double-buffer (32KB) with
// one-tile-ahead register prefetch.  40%8==0 gives natural bh->XCD affinity.
__global__ __launch_bounds__(256) void attn_kernel(
    const u16* __restrict__ qb, const u16* __restrict__ kb, const u16* __restrict__ vt,
    u16* __restrict__ y) {
  __shared__ __align__(16) u16 Ks[2][64 * 64];   // K[perm(key)][swz(d)], dbuf
  __shared__ __align__(16) u16 Vs[2][64 * 64];   // V^T[d][swz(key)], dbuf
  const int t = threadIdx.x;
  const int w = t >> 6, lane = t & 63, n16 = lane & 15, quad = lane >> 4;
  const int bh = blockIdx.x;
  const int qt = 31 - blockIdx.y;        // longest blocks first
  const int qb0 = qt * 64;
  const int b_ = bh / NHH, h = bh % NHH;

  // Q fragment (B-operand of S^T): B[n=q][k=d], q = qb0 + w*16 + n16
  bf16x8 aq[2];
  {
    const u16* qp = &qb[(bh * SS + qb0 + w * 16 + n16) * DHH];
    aq[0] = *(const bf16x8*)&qp[quad * 8];
    aq[1] = *(const bf16x8*)&qp[32 + quad * 8];
  }
  const int q_rel = w * 16 + n16;

  // staging: each thread moves 2x16B of K and 2x16B of V per tile
  const int c1 = 256 + t;
  const int row0 = t >> 3,  g0 = t & 7;        // row, 16B col-group
  const int row1 = c1 >> 3, g1 = c1 & 7;
  // key -> permuted LDS row: key = p*32 + quad*8 + b*4 + r  ->  (2p+b)*16 + quad*4 + r
  auto perm = [](int k) {
    int p = k >> 5, rem = k & 31, qd = rem >> 3, tt = rem & 7;
    return ((p << 1) | (tt >> 2)) * 16 + qd * 4 + (tt & 3);
  };
  const int prow0 = perm(row0), prow1 = perm(row1);
  // swizzled element offsets: col-group g at row r lives at (g ^ (r&7))*8
  const int kw0 = prow0 * 64 + ((g0 ^ (prow0 & 7)) * 8);
  const int kw1 = prow1 * 64 + ((g1 ^ (prow1 & 7)) * 8);
  const int vw0 = row0 * 64 + ((g0 ^ (row0 & 7)) * 8);
  const int vw1 = row1 * 64 + ((g1 ^ (row1 & 7)) * 8);
  const int col0 = g0 * 8, col1 = g1 * 8;      // global source cols (unswizzled)
  // swizzled read col offsets: group (4*ks+quad) at row parity n16&7
  const int rdA = (quad ^ (n16 & 7)) * 8;        // ks/p2 = 0
  const int rdB = ((4 + quad) ^ (n16 & 7)) * 8;  // ks/p2 = 1

  float4 fk0, fk1, fv0, fv1;
  fk0 = *(const float4*)&kb[(bh * SS + row0) * DHH + col0];
  fk1 = *(const float4*)&kb[(bh * SS + row1) * DHH + col1];
  fv0 = *(const float4*)&vt[(bh * DHH + row0) * SS + col0];
  fv1 = *(const float4*)&vt[(bh * DHH + row1) * SS + col1];
  *(float4*)&Ks[0][kw0] = fk0;
  *(float4*)&Ks[0][kw1] = fk1;
  *(float4*)&Vs[0][vw0] = fv0;
  *(float4*)&Vs[0][vw1] = fv1;

  float m_i = -1e30f, l_i = 0.f;
  f32x4 o[4];
  for (int db = 0; db < 4; db++) o[db] = f32x4{0.f, 0.f, 0.f, 0.f};

  for (int kt = 0; kt <= qt; ++kt) {
    __syncthreads();
    const int cur = kt & 1, nxt = cur ^ 1;
    if (kt < qt) {   // prefetch next tile (latency hidden behind compute)
      int kk = (kt + 1) * 64;
      fk0 = *(const float4*)&kb[(bh * SS + kk + row0) * DHH + col0];
      fk1 = *(const float4*)&kb[(bh * SS + kk + row1) * DHH + col1];
      fv0 = *(const float4*)&vt[(bh * DHH + row0) * SS + kk + col0];
      fv1 = *(const float4*)&vt[(bh * DHH + row1) * SS + kk + col1];
    }

    // S^T = K * Q^T : A=K (m=permuted key), B=Q (n=q); log2-domain scores
    f32x4 sc[4];
#pragma unroll
    for (int nb = 0; nb < 4; nb++) {
      f32x4 c = f32x4{0.f, 0.f, 0.f, 0.f};
      bf16x8 ak0 = *(const bf16x8*)&Ks[cur][(nb * 16 + n16) * 64 + rdA];
      c = __builtin_amdgcn_mfma_f32_16x16x32_bf16(ak0, aq[0], c, 0, 0, 0);
      bf16x8 ak1 = *(const bf16x8*)&Ks[cur][(nb * 16 + n16) * 64 + rdB];
      c = __builtin_amdgcn_mfma_f32_16x16x32_bf16(ak1, aq[1], c, 0, 0, 0);
      sc[nb] = c;
    }

    // causal mask only on the diagonal tile (uniform branch)
    if (kt == qt) {
#pragma unroll
      for (int nb = 0; nb < 4; nb++)
#pragma unroll
        for (int r = 0; r < 4; r++) {
          int key = ((nb >> 1) << 5) + quad * 8 + ((nb & 1) << 2) + r;
          if (key > q_rel) sc[nb][r] = -1e30f;
        }
    }

    // tile max (tree, v_max3-friendly), replicated over the 4 quads
    f32x4 mx;
#pragma unroll
    for (int r = 0; r < 4; r++)
      mx[r] = fmaxf(fmaxf(sc[0][r], sc[1][r]), fmaxf(sc[2][r], sc[3][r]));
    float rm = fmaxf(fmaxf(mx[0], mx[1]), fmaxf(mx[2], mx[3]));
    rm = fmaxf(rm, __shfl_xor(rm, 16));
    rm = fmaxf(rm, __shfl_xor(rm, 32));

    // T13 defer-max: skip the O/l rescale unless some lane's max grew by >8
    if (!__all(rm - m_i <= 8.0f)) {
      float mnew = fmaxf(m_i, rm);
      float alpha = EXP2(m_i - mnew);
      l_i *= alpha;
#pragma unroll
      for (int db = 0; db < 4; db++)
#pragma unroll
        for (int r = 0; r < 4; r++) o[db][r] *= alpha;
      m_i = mnew;
    }

    // P = 2^(S - m): 16 sub + 16 v_exp, row-sum via tree
    f32x4 ps[4];
#pragma unroll
    for (int nb = 0; nb < 4; nb++)
#pragma unroll
      for (int r = 0; r < 4; r++) ps[nb][r] = EXP2(sc[nb][r] - m_i);
    f32x4 sv;
#pragma unroll
    for (int r = 0; r < 4; r++)
      sv[r] = (ps[0][r] + ps[1][r]) + (ps[2][r] + ps[3][r]);
    float rs = (sv[0] + sv[1]) + (sv[2] + sv[3]);
    rs += __shfl_xor(rs, 16);
    rs += __shfl_xor(rs, 32);
    l_i += rs;

    // O^T += V^T * P^T : A=V^T (m=d), B=P^T (n=q, k=key) -- P already in B layout
#pragma unroll
    for (int p2 = 0; p2 < 2; p2++) {
      bf16x8 bp;
#pragma unroll
      for (int j = 0; j < 4; j++) {
        bp[j]     = (__bf16)ps[2 * p2][j];
        bp[4 + j] = (__bf16)ps[2 * p2 + 1][j];
      }
      const int rdV = p2 ? rdB : rdA;
#pragma unroll
      for (int db = 0; db < 4; db++) {
        bf16x8 av = *(const bf16x8*)&Vs[cur][(db * 16 + n16) * 64 + rdV];
        o[db] = __builtin_amdgcn_mfma_f32_16x16x32_bf16(av, bp, o[db], 0, 0, 0);
      }
    }

    if (kt < qt) {   // write prefetched tile into the other buffer
      *(float4*)&Ks[nxt][kw0] = fk0;
      *(float4*)&Ks[nxt][kw1] = fk1;
      *(float4*)&Vs[nxt][vw0] = fv0;
      *(float4*)&Vs[nxt][vw1] = fv1;
    }
  }

  // epilogue: O^T[d][q] -> y[token][h*64+d]; lane owns q = q_rel, d = db*16+quad*4+r
  const float inv = 1.0f / l_i;
  const int tok = b_ * SS + qb0 + w * 16 + n16;
#pragma unroll
  for (int db = 0; db < 4; db++) {
    bf16x4 pk = { (__bf16)(o[db][0] * inv), (__bf16)(o[db][1] * inv),
                  (__bf16)(o[db][2] * inv), (__bf16)(o[db][3] * inv) };
    *(bf16x4*)&y[tok * EE + h * DHH + db * 16 + quad * 4] = pk;
  }
}

// ---------------------------------------------------------------- proj GEMM
// out[8192,640] fp32 = y[8192,640] * wproj[640,640]^T.  R9 structure + T1
// XCD-chunked swizzle (nwg=320, 320/8=40 exact): each XCD owns 8 A-panels.
__global__ __launch_bounds__(256) void gemm_proj(
    const u16* __restrict__ A, const u16* __restrict__ Bt, float* __restrict__ out) {
  __shared__ __align__(16) u16 As[2][128 * 64];
  __shared__ __align__(16) u16 Bs[2][128 * 64];
  const int t = threadIdx.x;
  const int orig = blockIdx.x;
  const int newid = (orig & 7) * 40 + (orig >> 3);
  const int m0 = (newid / 5) * 128;
  const int n0 = (newid % 5) * 128;
  const int w = t >> 6, lane = t & 63, n16 = lane & 15, quad = lane >> 4;
  const int wm = w >> 1, wn = w & 1;

  const int sub = lane >> 3, cL = lane & 7;
  const int srcColE = (cL ^ sub) * 8;
  const int rd0 = (quad ^ (n16 & 7)) * 8;
  const int rd1 = ((4 + quad) ^ (n16 & 7)) * 8;

  f32x4 acc[4][4];
  for (int i = 0; i < 4; i++)
    for (int j = 0; j < 4; j++) acc[i][j] = f32x4{0.f, 0.f, 0.f, 0.f};

#pragma unroll
  for (int i = 0; i < 4; ++i) {
    int c = w * 4 + i, row = c * 8 + sub;
    gl_lds16(&A[(m0 + row) * 640 + srcColE], &As[0][c * 512]);
    gl_lds16(&Bt[(n0 + row) * 640 + srcColE], &Bs[0][c * 512]);
  }
  __syncthreads();

  for (int kt = 0; kt < 10; ++kt) {
    const int cur = kt & 1, nxt = cur ^ 1;
    if (kt < 9) {
#pragma unroll
      for (int i = 0; i < 4; ++i) {
        int c = w * 4 + i, row = c * 8 + sub;
        gl_lds16(&A[(m0 + row) * 640 + (kt + 1) * 64 + srcColE], &As[nxt][c * 512]);
        gl_lds16(&Bt[(n0 + row) * 640 + (kt + 1) * 64 + srcColE], &Bs[nxt][c * 512]);
      }
    }
#pragma unroll
    for (int ks = 0; ks < 2; ++ks) {
      const int rd = ks ? rd1 : rd0;
      bf16x8 a[4], b[4];
      for (int mi = 0; mi < 4; mi++)
        a[mi] = *(const bf16x8*)&As[cur][(wm * 64 + mi * 16 + n16) * 64 + rd];
      for (int ni = 0; ni < 4; ni++)
        b[ni] = *(const bf16x8*)&Bs[cur][(wn * 64 + ni * 16 + n16) * 64 + rd];
      for (int mi = 0; mi < 4; mi++)
        for (int ni = 0; ni < 4; ni++)
          acc[mi][ni] = __builtin_amdgcn_mfma_f32_16x16x32_bf16(a[mi], b[ni], acc[mi][ni], 0, 0, 0);
    }
    __syncthreads();
  }

  for (int ni = 0; ni < 4; ni++) {
    int col = n0 + wn * 64 + ni * 16 + n16;
    for (int mi = 0; mi < 4; mi++) {
      int rowb = m0 + wm * 64 + mi * 16 + quad * 4;
      f32x4 c = acc[mi][ni];
      for (int r = 0; r < 4; r++) out[(rowb + r) * 640 + col] = c[r];
    }
  }
}

// ---------------------------------------------------------------- launch
extern "C" void kernel_launch(void* const* d_in, const int* in_sizes, int n_in,
                              void* d_out, int out_size, void* d_ws, size_t ws_size,
                              hipStream_t stream) {
  const float* x     = (const float*)d_in[0];   // [4,2048,640]
  const float* wqkv  = (const float*)d_in[1];   // [1920,640]
  const float* wproj = (const float*)d_in[2];   // [640,640]
  float* out = (float*)d_out;

  char* ws = (char*)d_ws;
  u16* xb     = (u16*)(ws + 0);            // 10,485,760 B
  u16* wqkvb  = (u16*)(ws + 10485760);     //  2,457,600 B
  u16* wprojb = (u16*)(ws + 12943360);     //    819,200 B
  u16* qbuf   = (u16*)(ws + 13762560);     // 10,485,760 B  [bh][s][d]
  u16* kbuf   = (u16*)(ws + 24248320);     // 10,485,760 B  [bh][s][d]
  u16* vtb    = (u16*)(ws + 34734080);     // 10,485,760 B  [bh][d][s]
  u16* ybuf   = (u16*)(ws + 45219840);     // 10,485,760 B  [tok][e]

  convert_all<<<6720, 256, 0, stream>>>(x, wqkv, wproj, xb, wqkvb, wprojb);

  gemm_qkv<<<960, 256, 0, stream>>>(xb, wqkvb, qbuf, kbuf, vtb);
  attn_kernel<<<dim3(40, 32), 256, 0, stream>>>(qbuf, kbuf, vtb, ybuf);
  gemm_proj<<<320, 256, 0, stream>>>(ybuf, wprojb, out);
}